// Round 8
// baseline (1209.020 us; speedup 1.0000x reference)
//
#include <hip/hip_runtime.h>
#include <hip/hip_bf16.h>
#include <math.h>

// ---------------------------------------------------------------------------
// KAN 2-layer forward, R8 = R5 pipeline, INSTRUMENTATION ROUND.
// Each kernel repeats its (idempotent) work REP_* times so its single dispatch
// exceeds the harness's 42us poison-fills and appears in rocprof top-5 with
// counters.  True per-kernel time = dur_us / REP.  Numerics identical to R5.
// ---------------------------------------------------------------------------

#define B_DIM   128
#define IN1     3072
#define OUT1    256
#define NB      8
#define OUT2    10

#define KTOT    27648            // 9 * 3072
#define ROWB    55296            // KTOT * 2 bytes per row
#define SPLITK  108              // k-chunks (each 256 k = 4 stages of 64 k)
#define BN      64

#define REP_A   48
#define REP_W   8
#define REP_G   20
#define REP_R   24

typedef short  bf16x8 __attribute__((ext_vector_type(8)));
typedef float  f32x4  __attribute__((ext_vector_type(4)));
typedef unsigned short ushort_t;
typedef unsigned int u32;

__device__ __forceinline__ ushort_t f2bf(float f) {
    union { __hip_bfloat16 h; ushort_t u; } v;
    v.h = __float2bfloat16(f);
    return v.u;
}
__device__ __forceinline__ float bf2f(ushort_t h) {
    union { float f; u32 u; } v; v.u = ((u32)h) << 16;
    return v.f;
}

__device__ __forceinline__ void gl_lds16(const void* g, void* l) {
    __builtin_amdgcn_global_load_lds(
        (const __attribute__((address_space(1))) u32*)g,
        (__attribute__((address_space(3))) u32*)l, 16, 0, 0);
}

// cardinal cubic B-spline basis (8 funcs) + silu, closed form (== Cox-de Boor
// recursion of the reference on the uniform extended grid [-2.2,2.2], h=0.4).
__device__ __forceinline__ void basis_silu(float x, float w[8], float& sil) {
    sil = x / (1.0f + __expf(-x));
    float u  = (x + 2.2f) * 2.5f;
    float uf = floorf(u);
    int   j  = (int)uf;
    float t  = u - uf;
    float omt = 1.0f - t;
    float t2 = t * t, t3 = t2 * t;
    float w0 = omt * omt * omt * (1.0f / 6.0f);
    float w1 = (3.0f * t3 - 6.0f * t2 + 4.0f) * (1.0f / 6.0f);
    float w2 = (-3.0f * t3 + 3.0f * t2 + 3.0f * t + 1.0f) * (1.0f / 6.0f);
    float w3 = t3 * (1.0f / 6.0f);
    bool valid = (u >= 0.0f) && (u < 11.0f);
#pragma unroll
    for (int g = 0; g < 8; ++g) {
        int m = g - j + 3;
        float v = (m == 0) ? w0 : (m == 1) ? w1 : (m == 2) ? w2 : (m == 3) ? w3 : 0.0f;
        w[g] = valid ? v : 0.0f;
    }
}

__device__ __forceinline__ float selu_f(float x) {
    const float scale = 1.0507009873554805f;
    const float alpha = 1.6732632423543772f;
    return (x > 0.0f) ? scale * x : scale * alpha * (__expf(x) - 1.0f);
}

// ---------------------------------------------------------------------------
// kconv_a: thread -> (b, ig of 8 i).  Writes 9 bands x ushort8 (swizzled quad).
// ---------------------------------------------------------------------------
__global__ __launch_bounds__(128) void kconv_a(const float* __restrict__ x,
                                               char* __restrict__ Ag) {
    const int gid = blockIdx.x * 128 + threadIdx.x;        // 0..49151
    const int b  = gid / 384;
    const int ig = gid - b * 384;
    const int i0 = ig * 8;

#pragma unroll 1
    for (int rep = 0; rep < REP_A; ++rep) {
        asm volatile("" ::: "memory");
        float4 x0 = *reinterpret_cast<const float4*>(x + (size_t)b * IN1 + i0);
        float4 x1 = *reinterpret_cast<const float4*>(x + (size_t)b * IN1 + i0 + 4);
        float xa[8] = {x0.x, x0.y, x0.z, x0.w, x1.x, x1.y, x1.z, x1.w};

        float bs[8][8], sil[8];
#pragma unroll
        for (int p = 0; p < 8; ++p) basis_silu(xa[p], bs[p], sil[p]);

        char* rowp = Ag + (size_t)b * ROWB;
        const int qsw = ((ig & 7) ^ (b & 7)) << 4;
#pragma unroll
        for (int s = 0; s < 9; ++s) {
            ushort_t v[8];
#pragma unroll
            for (int p = 0; p < 8; ++p)
                v[p] = f2bf((s < 8) ? bs[p][s] : sil[p]);
            *reinterpret_cast<uint4*>(rowp + (s * 48 + (ig >> 3)) * 128 + qsw) =
                *reinterpret_cast<const uint4*>(v);
        }
    }
}

// ---------------------------------------------------------------------------
// kconv_w: thread -> (o, ig of 8 i).  W[k][o]: slot<8 = coef*ssp, slot8 = sb.
// ---------------------------------------------------------------------------
__global__ __launch_bounds__(128) void kconv_w(const float* __restrict__ coef1,
                                               const float* __restrict__ sb1,
                                               const float* __restrict__ ssp1,
                                               char* __restrict__ Wg) {
    const int gid = blockIdx.x * 128 + threadIdx.x;        // 0..98303
    const int o  = gid / 384;
    const int ig = gid - o * 384;
    const int i0 = ig * 8;

#pragma unroll 1
    for (int rep = 0; rep < REP_W; ++rep) {
        asm volatile("" ::: "memory");
        float cf[8][8], sspv[8], sbv[8];
#pragma unroll
        for (int p = 0; p < 8; ++p) {
            const float* cp = coef1 + ((size_t)o * IN1 + i0 + p) * NB;
            float4 c0 = *reinterpret_cast<const float4*>(cp);
            float4 c1 = *reinterpret_cast<const float4*>(cp + 4);
            cf[p][0] = c0.x; cf[p][1] = c0.y; cf[p][2] = c0.z; cf[p][3] = c0.w;
            cf[p][4] = c1.x; cf[p][5] = c1.y; cf[p][6] = c1.z; cf[p][7] = c1.w;
        }
        {
            float4 s0 = *reinterpret_cast<const float4*>(ssp1 + (size_t)o * IN1 + i0);
            float4 s1 = *reinterpret_cast<const float4*>(ssp1 + (size_t)o * IN1 + i0 + 4);
            sspv[0]=s0.x; sspv[1]=s0.y; sspv[2]=s0.z; sspv[3]=s0.w;
            sspv[4]=s1.x; sspv[5]=s1.y; sspv[6]=s1.z; sspv[7]=s1.w;
            float4 b0 = *reinterpret_cast<const float4*>(sb1 + (size_t)o * IN1 + i0);
            float4 b1 = *reinterpret_cast<const float4*>(sb1 + (size_t)o * IN1 + i0 + 4);
            sbv[0]=b0.x; sbv[1]=b0.y; sbv[2]=b0.z; sbv[3]=b0.w;
            sbv[4]=b1.x; sbv[5]=b1.y; sbv[6]=b1.z; sbv[7]=b1.w;
        }

        char* rowp = Wg + (size_t)o * ROWB;
        const int qsw = ((ig & 7) ^ (o & 7)) << 4;
#pragma unroll
        for (int s = 0; s < 9; ++s) {
            ushort_t v[8];
#pragma unroll
            for (int p = 0; p < 8; ++p)
                v[p] = f2bf((s < 8) ? cf[p][s] * sspv[p] : sbv[p]);
            *reinterpret_cast<uint4*>(rowp + (s * 48 + (ig >> 3)) * 128 + qsw) =
                *reinterpret_cast<const uint4*>(v);
        }
    }
}

// ---------------------------------------------------------------------------
// kgemm: C(128 x 64-per-nt) += A(128,256k) * W(256k,64).  512 thr, grid (4,108).
//   Stage = 64 k (one 128B chunk per row).  2-buffer LDS, counted vmcnt.
// ---------------------------------------------------------------------------
__global__ __launch_bounds__(512) void kgemm(const char* __restrict__ Ag,
                                             const char* __restrict__ Wg,
                                             ushort_t* __restrict__ partial) {
    __shared__ __align__(16) char lds[2][24576];   // per buf: A 16K | W 8K

    const int tid = threadIdx.x;
    const int w   = tid >> 6, l = tid & 63;
    const int nt  = blockIdx.x, kc = blockIdx.y;
    const int o0  = nt * BN;

    const int ar0 = tid >> 3;                 // A round 0: rows 0..63
    const int ar1 = 64 + (tid >> 3);          // A round 1: rows 64..127
    const int aq  = tid & 7;
    const char* Asrc0 = Ag + (size_t)ar0 * ROWB + ((aq ^ (ar0 & 7)) << 4);
    const char* Asrc1 = Ag + (size_t)ar1 * ROWB + ((aq ^ (ar1 & 7)) << 4);
    const int wr = tid >> 3;                  // W rows 0..63
    const char* Wsrc = Wg + (size_t)(o0 + wr) * ROWB + ((aq ^ (wr & 7)) << 4);

    const int mq = w >> 1, nq = w & 1;
    const int r16 = l & 15, k16 = l >> 4;

#define ISSUE(ss, buf)                                                        \
    {                                                                         \
        const int cb = (kc * 4 + (ss)) * 128;                                 \
        char* base = &lds[buf][0];                                            \
        gl_lds16(Asrc0 + cb, base + w * 1024);                                \
        gl_lds16(Asrc1 + cb, base + 8192 + w * 1024);                         \
        gl_lds16(Wsrc  + cb, base + 16384 + w * 1024);                        \
    }

#pragma unroll 1
    for (int rep = 0; rep < REP_G; ++rep) {
        asm volatile("" ::: "memory");
        f32x4 acc[2][2];
#pragma unroll
        for (int a = 0; a < 2; ++a)
#pragma unroll
            for (int bq = 0; bq < 2; ++bq) acc[a][bq] = (f32x4){0.f, 0.f, 0.f, 0.f};

        ISSUE(0, 0)
        ISSUE(1, 1)

#pragma unroll
        for (int s = 0; s < 4; ++s) {
            if (s < 3) { asm volatile("s_waitcnt vmcnt(3)" ::: "memory"); }
            else       { asm volatile("s_waitcnt vmcnt(0)" ::: "memory"); }
            __builtin_amdgcn_s_barrier();
            asm volatile("" ::: "memory");

            const char* Ab = &lds[s & 1][0];
            const char* Wb = &lds[s & 1][16384];
#pragma unroll
            for (int ks = 0; ks < 2; ++ks) {
                const int qf = ks * 4 + k16;
                bf16x8 bf[2], af[2];
#pragma unroll
                for (int bq = 0; bq < 2; ++bq) {
                    const int rn = nq * 32 + bq * 16 + r16;
                    bf[bq] = *reinterpret_cast<const bf16x8*>(Wb + rn * 128 + ((qf ^ (rn & 7)) << 4));
                }
#pragma unroll
                for (int a = 0; a < 2; ++a) {
                    const int rm = mq * 32 + a * 16 + r16;
                    af[a] = *reinterpret_cast<const bf16x8*>(Ab + rm * 128 + ((qf ^ (rm & 7)) << 4));
                }
#pragma unroll
                for (int a = 0; a < 2; ++a)
#pragma unroll
                    for (int bq = 0; bq < 2; ++bq)
                        acc[a][bq] = __builtin_amdgcn_mfma_f32_16x16x32_bf16(af[a], bf[bq], acc[a][bq], 0, 0, 0);
            }

            __builtin_amdgcn_s_barrier();
            asm volatile("" ::: "memory");
            if (s == 0) ISSUE(2, 0)
            if (s == 1) ISSUE(3, 1)
        }

        // epilogue: bf16 partial [kc][b][o]
        ushort_t* pp = partial + (size_t)kc * (B_DIM * OUT1);
#pragma unroll
        for (int a = 0; a < 2; ++a) {
#pragma unroll
            for (int bq = 0; bq < 2; ++bq) {
                const int col = o0 + nq * 32 + bq * 16 + r16;
#pragma unroll
                for (int r = 0; r < 4; ++r) {
                    const int row = mq * 32 + a * 16 + k16 * 4 + r;
                    pp[(size_t)row * OUT1 + col] = f2bf(acc[a][bq][r]);
                }
            }
        }
    }
#undef ISSUE
}

// ---------------------------------------------------------------------------
// kreduce: sum 108 partials (4-way split) -> h, selu, layer2.
// ---------------------------------------------------------------------------
#define CPG (SPLITK / 4)   // 27

__global__ __launch_bounds__(1024) void kreduce(const ushort_t* __restrict__ partial,
                                                const float* __restrict__ coef2,
                                                const float* __restrict__ sb2,
                                                const float* __restrict__ ssp2,
                                                float* __restrict__ out) {
    const int b = blockIdx.x;
    const int t = threadIdx.x;
    const int o = t & 255;
    const int g = t >> 8;                    // 0..3
    __shared__ float hred[4][OUT1];
    __shared__ float red[16][OUT2];

#pragma unroll 1
    for (int rep = 0; rep < REP_R; ++rep) {
        asm volatile("" ::: "memory");
        const ushort_t* pp = partial + ((size_t)g * CPG * B_DIM + b) * OUT1 + o;
        float sum = 0.0f;
#pragma unroll
        for (int c = 0; c < CPG; ++c)
            sum += bf2f(pp[(size_t)c * (B_DIM * OUT1)]);

        hred[g][o] = sum;
        __syncthreads();
        const float hv = hred[0][o] + hred[1][o] + hred[2][o] + hred[3][o];

        const float sh = selu_f(hv);
        float w8[8], sil;
        basis_silu(sh, w8, sil);

        float accs[OUT2];
#pragma unroll
        for (int oo = 0; oo < OUT2; ++oo) {
            const float* cp = coef2 + ((size_t)oo * OUT1 + o) * NB;
            float4 c0 = *reinterpret_cast<const float4*>(cp);
            float4 c1 = *reinterpret_cast<const float4*>(cp + 4);
            float dot = w8[0] * c0.x + w8[1] * c0.y + w8[2] * c0.z + w8[3] * c0.w +
                        w8[4] * c1.x + w8[5] * c1.y + w8[6] * c1.z + w8[7] * c1.w;
            accs[oo] = sb2[oo * OUT1 + o] * sil + ssp2[oo * OUT1 + o] * dot;
        }

        const int lane = t & 63, wv = t >> 6;
#pragma unroll
        for (int oo = 0; oo < OUT2; ++oo) {
            float v = accs[oo];
#pragma unroll
            for (int off = 32; off >= 1; off >>= 1) v += __shfl_xor(v, off, 64);
            if (lane == 0) red[wv][oo] = v;
        }
        __syncthreads();
        if (t < OUT2)
            out[b * OUT2 + t] = red[0][t] + red[1][t] + red[2][t] + red[3][t];
        __syncthreads();
    }
}

// ---------------------------------------------------------------------------
extern "C" void kernel_launch(void* const* d_in, const int* in_sizes, int n_in,
                              void* d_out, int out_size, void* d_ws, size_t ws_size,
                              hipStream_t stream) {
    const float* x     = (const float*)d_in[0];
    const float* coef1 = (const float*)d_in[1];
    const float* sb1   = (const float*)d_in[2];
    const float* ssp1  = (const float*)d_in[3];
    const float* coef2 = (const float*)d_in[4];
    const float* sb2   = (const float*)d_in[5];
    const float* ssp2  = (const float*)d_in[6];
    float* out = (float*)d_out;

    char*     Ag      = (char*)d_ws;                             // 7,077,888 B
    char*     Wg      = Ag + (size_t)B_DIM * ROWB;               // 14,155,776 B
    ushort_t* partial = (ushort_t*)(Wg + (size_t)OUT1 * ROWB);   // 7,077,888 B

    kconv_a<<<384, 128, 0, stream>>>(x, Ag);
    kconv_w<<<768, 128, 0, stream>>>(coef1, sb1, ssp1, Wg);
    kgemm<<<dim3(OUT1 / BN, SPLITK), 512, 0, stream>>>(Ag, Wg, partial);
    kreduce<<<B_DIM, 1024, 0, stream>>>(partial, coef2, sb2, ssp2, out);
}

// Round 9
// 43.210 us; speedup vs baseline: 27.9799x; 27.9799x over previous
//
#include <hip/hip_runtime.h>
#include <hip/hip_bf16.h>
#include <math.h>

// ---------------------------------------------------------------------------
// KAN 2-layer forward, R9: R5 pipeline minus the 25us reduce.
//   kconv  : dual-role streaming pass.  Blocks 0..383: x -> Ag bf16 (basis+silu,
//            banded, swizzled) and blocks 0..255 also zero h.  Blocks 384..1151:
//            coef1*ssp1|sb1 -> Wg bf16 (swizzled).
//   kgemm  : C = A*W^T MFMA, split-K=108, global_load_lds pipeline,
//            epilogue = f32 atomicAdd straight into h (no partial buffer).
//   klayer2: h -> selu -> basis -> layer2 dot -> out.
// ---------------------------------------------------------------------------

#define B_DIM   128
#define IN1     3072
#define OUT1    256
#define NB      8
#define OUT2    10

#define KTOT    27648            // 9 * 3072
#define ROWB    55296            // KTOT * 2 bytes per row
#define SPLITK  108              // k-chunks (each 256 k = 4 stages of 64 k)
#define BN      64

typedef short  bf16x8 __attribute__((ext_vector_type(8)));
typedef float  f32x4  __attribute__((ext_vector_type(4)));
typedef unsigned short ushort_t;
typedef unsigned int u32;

__device__ __forceinline__ ushort_t f2bf(float f) {
    union { __hip_bfloat16 h; ushort_t u; } v;
    v.h = __float2bfloat16(f);
    return v.u;
}

__device__ __forceinline__ void gl_lds16(const void* g, void* l) {
    __builtin_amdgcn_global_load_lds(
        (const __attribute__((address_space(1))) u32*)g,
        (__attribute__((address_space(3))) u32*)l, 16, 0, 0);
}

// cardinal cubic B-spline basis (8 funcs) + silu, closed form (== Cox-de Boor
// recursion of the reference on the uniform extended grid [-2.2,2.2], h=0.4).
__device__ __forceinline__ void basis_silu(float x, float w[8], float& sil) {
    sil = x / (1.0f + __expf(-x));
    float u  = (x + 2.2f) * 2.5f;
    float uf = floorf(u);
    int   j  = (int)uf;
    float t  = u - uf;
    float omt = 1.0f - t;
    float t2 = t * t, t3 = t2 * t;
    float w0 = omt * omt * omt * (1.0f / 6.0f);
    float w1 = (3.0f * t3 - 6.0f * t2 + 4.0f) * (1.0f / 6.0f);
    float w2 = (-3.0f * t3 + 3.0f * t2 + 3.0f * t + 1.0f) * (1.0f / 6.0f);
    float w3 = t3 * (1.0f / 6.0f);
    bool valid = (u >= 0.0f) && (u < 11.0f);
#pragma unroll
    for (int g = 0; g < 8; ++g) {
        int m = g - j + 3;
        float v = (m == 0) ? w0 : (m == 1) ? w1 : (m == 2) ? w2 : (m == 3) ? w3 : 0.0f;
        w[g] = valid ? v : 0.0f;
    }
}

__device__ __forceinline__ float selu_f(float x) {
    const float scale = 1.0507009873554805f;
    const float alpha = 1.6732632423543772f;
    return (x > 0.0f) ? scale * x : scale * alpha * (__expf(x) - 1.0f);
}

// ---------------------------------------------------------------------------
// kconv: 1152 blocks x 128 thr.
//   blocks 0..383   : A-conversion (thread -> (b, 8 inputs)); blocks 0..255
//                     additionally zero h (128 f32 each).
//   blocks 384..1151: W-conversion (thread -> (o, 8 inputs)).
// ---------------------------------------------------------------------------
__global__ __launch_bounds__(128) void kconv(const float* __restrict__ x,
                                             const float* __restrict__ coef1,
                                             const float* __restrict__ sb1,
                                             const float* __restrict__ ssp1,
                                             char* __restrict__ Ag,
                                             char* __restrict__ Wg,
                                             float* __restrict__ h) {
    const int blk = blockIdx.x;
    if (blk < 384) {
        if (blk < 256) h[blk * 128 + threadIdx.x] = 0.0f;

        const int gid = blk * 128 + threadIdx.x;           // 0..49151
        const int b  = gid / 384;
        const int ig = gid - b * 384;
        const int i0 = ig * 8;

        float4 x0 = *reinterpret_cast<const float4*>(x + (size_t)b * IN1 + i0);
        float4 x1 = *reinterpret_cast<const float4*>(x + (size_t)b * IN1 + i0 + 4);
        float xa[8] = {x0.x, x0.y, x0.z, x0.w, x1.x, x1.y, x1.z, x1.w};

        float bs[8][8], sil[8];
#pragma unroll
        for (int p = 0; p < 8; ++p) basis_silu(xa[p], bs[p], sil[p]);

        char* rowp = Ag + (size_t)b * ROWB;
        const int qsw = ((ig & 7) ^ (b & 7)) << 4;
#pragma unroll
        for (int s = 0; s < 9; ++s) {
            ushort_t v[8];
#pragma unroll
            for (int p = 0; p < 8; ++p)
                v[p] = f2bf((s < 8) ? bs[p][s] : sil[p]);
            *reinterpret_cast<uint4*>(rowp + (s * 48 + (ig >> 3)) * 128 + qsw) =
                *reinterpret_cast<const uint4*>(v);
        }
    } else {
        const int gid = (blk - 384) * 128 + threadIdx.x;   // 0..98303
        const int o  = gid / 384;
        const int ig = gid - o * 384;
        const int i0 = ig * 8;

        float cf[8][8], sspv[8], sbv[8];
#pragma unroll
        for (int p = 0; p < 8; ++p) {
            const float* cp = coef1 + ((size_t)o * IN1 + i0 + p) * NB;
            float4 c0 = *reinterpret_cast<const float4*>(cp);
            float4 c1 = *reinterpret_cast<const float4*>(cp + 4);
            cf[p][0] = c0.x; cf[p][1] = c0.y; cf[p][2] = c0.z; cf[p][3] = c0.w;
            cf[p][4] = c1.x; cf[p][5] = c1.y; cf[p][6] = c1.z; cf[p][7] = c1.w;
        }
        {
            float4 s0 = *reinterpret_cast<const float4*>(ssp1 + (size_t)o * IN1 + i0);
            float4 s1 = *reinterpret_cast<const float4*>(ssp1 + (size_t)o * IN1 + i0 + 4);
            sspv[0]=s0.x; sspv[1]=s0.y; sspv[2]=s0.z; sspv[3]=s0.w;
            sspv[4]=s1.x; sspv[5]=s1.y; sspv[6]=s1.z; sspv[7]=s1.w;
            float4 b0 = *reinterpret_cast<const float4*>(sb1 + (size_t)o * IN1 + i0);
            float4 b1 = *reinterpret_cast<const float4*>(sb1 + (size_t)o * IN1 + i0 + 4);
            sbv[0]=b0.x; sbv[1]=b0.y; sbv[2]=b0.z; sbv[3]=b0.w;
            sbv[4]=b1.x; sbv[5]=b1.y; sbv[6]=b1.z; sbv[7]=b1.w;
        }

        char* rowp = Wg + (size_t)o * ROWB;
        const int qsw = ((ig & 7) ^ (o & 7)) << 4;
#pragma unroll
        for (int s = 0; s < 9; ++s) {
            ushort_t v[8];
#pragma unroll
            for (int p = 0; p < 8; ++p)
                v[p] = f2bf((s < 8) ? cf[p][s] * sspv[p] : sbv[p]);
            *reinterpret_cast<uint4*>(rowp + (s * 48 + (ig >> 3)) * 128 + qsw) =
                *reinterpret_cast<const uint4*>(v);
        }
    }
}

// ---------------------------------------------------------------------------
// kgemm: C(128 x 64-per-nt) += A(128,256k) * W(256k,64).  512 thr, grid (4,108).
//   Stage = 64 k (one 128B chunk per row).  2-buffer LDS, counted vmcnt.
//   Epilogue: f32 atomicAdd into h.
// ---------------------------------------------------------------------------
__global__ __launch_bounds__(512) void kgemm(const char* __restrict__ Ag,
                                             const char* __restrict__ Wg,
                                             float* __restrict__ h) {
    __shared__ __align__(16) char lds[2][24576];   // per buf: A 16K | W 8K

    const int tid = threadIdx.x;
    const int w   = tid >> 6, l = tid & 63;
    const int nt  = blockIdx.x, kc = blockIdx.y;
    const int o0  = nt * BN;

    const int ar0 = tid >> 3;                 // A round 0: rows 0..63
    const int ar1 = 64 + (tid >> 3);          // A round 1: rows 64..127
    const int aq  = tid & 7;
    const char* Asrc0 = Ag + (size_t)ar0 * ROWB + ((aq ^ (ar0 & 7)) << 4);
    const char* Asrc1 = Ag + (size_t)ar1 * ROWB + ((aq ^ (ar1 & 7)) << 4);
    const int wr = tid >> 3;                  // W rows 0..63
    const char* Wsrc = Wg + (size_t)(o0 + wr) * ROWB + ((aq ^ (wr & 7)) << 4);

#define ISSUE(ss, buf)                                                        \
    {                                                                         \
        const int cb = (kc * 4 + (ss)) * 128;                                 \
        char* base = &lds[buf][0];                                            \
        gl_lds16(Asrc0 + cb, base + w * 1024);                                \
        gl_lds16(Asrc1 + cb, base + 8192 + w * 1024);                         \
        gl_lds16(Wsrc  + cb, base + 16384 + w * 1024);                        \
    }

    f32x4 acc[2][2];
#pragma unroll
    for (int a = 0; a < 2; ++a)
#pragma unroll
        for (int bq = 0; bq < 2; ++bq) acc[a][bq] = (f32x4){0.f, 0.f, 0.f, 0.f};

    const int mq = w >> 1, nq = w & 1;
    const int r16 = l & 15, k16 = l >> 4;

    ISSUE(0, 0)
    ISSUE(1, 1)

#pragma unroll
    for (int s = 0; s < 4; ++s) {
        if (s < 3) { asm volatile("s_waitcnt vmcnt(3)" ::: "memory"); }
        else       { asm volatile("s_waitcnt vmcnt(0)" ::: "memory"); }
        __builtin_amdgcn_s_barrier();
        asm volatile("" ::: "memory");

        const char* Ab = &lds[s & 1][0];
        const char* Wb = &lds[s & 1][16384];
#pragma unroll
        for (int ks = 0; ks < 2; ++ks) {
            const int qf = ks * 4 + k16;
            bf16x8 bf[2], af[2];
#pragma unroll
            for (int bq = 0; bq < 2; ++bq) {
                const int rn = nq * 32 + bq * 16 + r16;
                bf[bq] = *reinterpret_cast<const bf16x8*>(Wb + rn * 128 + ((qf ^ (rn & 7)) << 4));
            }
#pragma unroll
            for (int a = 0; a < 2; ++a) {
                const int rm = mq * 32 + a * 16 + r16;
                af[a] = *reinterpret_cast<const bf16x8*>(Ab + rm * 128 + ((qf ^ (rm & 7)) << 4));
            }
#pragma unroll
            for (int a = 0; a < 2; ++a)
#pragma unroll
                for (int bq = 0; bq < 2; ++bq)
                    acc[a][bq] = __builtin_amdgcn_mfma_f32_16x16x32_bf16(af[a], bf[bq], acc[a][bq], 0, 0, 0);
        }

        __builtin_amdgcn_s_barrier();
        asm volatile("" ::: "memory");
        if (s == 0) ISSUE(2, 0)
        if (s == 1) ISSUE(3, 1)
    }
#undef ISSUE

    // epilogue: accumulate into h via device-scope f32 atomics
#pragma unroll
    for (int a = 0; a < 2; ++a) {
#pragma unroll
        for (int bq = 0; bq < 2; ++bq) {
            const int col = o0 + nq * 32 + bq * 16 + r16;
#pragma unroll
            for (int r = 0; r < 4; ++r) {
                const int row = mq * 32 + a * 16 + k16 * 4 + r;
                atomicAdd(&h[(size_t)row * OUT1 + col], acc[a][bq][r]);
            }
        }
    }
}

// ---------------------------------------------------------------------------
// klayer2: h -> selu -> basis -> layer2 -> out.  One block per b, 256 thr.
// ---------------------------------------------------------------------------
__global__ __launch_bounds__(256) void klayer2(const float* __restrict__ h,
                                               const float* __restrict__ coef2,
                                               const float* __restrict__ sb2,
                                               const float* __restrict__ ssp2,
                                               float* __restrict__ out) {
    const int b = blockIdx.x;
    const int t = threadIdx.x;               // t = o1 (h index), 0..255
    const float hv = h[b * OUT1 + t];
    const float sh = selu_f(hv);
    float w8[8], sil;
    basis_silu(sh, w8, sil);

    float accs[OUT2];
#pragma unroll
    for (int oo = 0; oo < OUT2; ++oo) {
        const float* cp = coef2 + ((size_t)oo * OUT1 + t) * NB;
        float4 c0 = *reinterpret_cast<const float4*>(cp);
        float4 c1 = *reinterpret_cast<const float4*>(cp + 4);
        float dot = w8[0] * c0.x + w8[1] * c0.y + w8[2] * c0.z + w8[3] * c0.w +
                    w8[4] * c1.x + w8[5] * c1.y + w8[6] * c1.z + w8[7] * c1.w;
        accs[oo] = sb2[oo * OUT1 + t] * sil + ssp2[oo * OUT1 + t] * dot;
    }

    __shared__ float red[4][OUT2];
    const int lane = t & 63, wv = t >> 6;
#pragma unroll
    for (int oo = 0; oo < OUT2; ++oo) {
        float v = accs[oo];
#pragma unroll
        for (int off = 32; off >= 1; off >>= 1) v += __shfl_xor(v, off, 64);
        if (lane == 0) red[wv][oo] = v;
    }
    __syncthreads();
    if (t < OUT2)
        out[b * OUT2 + t] = red[0][t] + red[1][t] + red[2][t] + red[3][t];
}

// ---------------------------------------------------------------------------
extern "C" void kernel_launch(void* const* d_in, const int* in_sizes, int n_in,
                              void* d_out, int out_size, void* d_ws, size_t ws_size,
                              hipStream_t stream) {
    const float* x     = (const float*)d_in[0];
    const float* coef1 = (const float*)d_in[1];
    const float* sb1   = (const float*)d_in[2];
    const float* ssp1  = (const float*)d_in[3];
    const float* coef2 = (const float*)d_in[4];
    const float* sb2   = (const float*)d_in[5];
    const float* ssp2  = (const float*)d_in[6];
    float* out = (float*)d_out;

    char*  Ag = (char*)d_ws;                          // 7,077,888 B
    char*  Wg = Ag + (size_t)B_DIM * ROWB;            // 14,155,776 B
    float* h  = (float*)(Wg + (size_t)OUT1 * ROWB);   //   131,072 B

    kconv<<<1152, 128, 0, stream>>>(x, coef1, sb1, ssp1, Ag, Wg, h);
    kgemm<<<dim3(OUT1 / BN, SPLITK), 512, 0, stream>>>(Ag, Wg, h);
    klayer2<<<B_DIM, 256, 0, stream>>>(h, coef2, sb2, ssp2, out);
}

// Round 10
// 36.268 us; speedup vs baseline: 33.3353x; 1.1914x over previous
//
#include <hip/hip_runtime.h>
#include <hip/hip_bf16.h>
#include <math.h>

// ---------------------------------------------------------------------------
// KAN 2-layer forward, R10: R5 pipeline with the reduce done right.
//   kconv   : dual-role streaming pass.  Blocks 0..383: x -> Ag bf16 (basis+
//             silu, banded, swizzled).  Blocks 384..1151: coef1*ssp1|sb1 -> Wg.
//   kgemm   : C = A*W^T MFMA, split-K=108, global_load_lds pipeline,
//             bf16 partial[kc][b][o] (coalesced stores, no atomics).
//   klayer2r: per-b block; 4 waves sum kc%4 partials with 512B-contiguous
//             wave-loads (27 independent loads each) -> LDS -> h -> selu ->
//             basis -> layer2 -> out.  (R8 autopsy: old reduce was 128 blocks
//             of strided 128B loads = 287 GB/s; this is the fix.)
// ---------------------------------------------------------------------------

#define B_DIM   128
#define IN1     3072
#define OUT1    256
#define NB      8
#define OUT2    10

#define KTOT    27648            // 9 * 3072
#define ROWB    55296            // KTOT * 2 bytes per row
#define SPLITK  108              // k-chunks (each 256 k = 4 stages of 64 k)
#define BN      64

typedef short  bf16x8 __attribute__((ext_vector_type(8)));
typedef float  f32x4  __attribute__((ext_vector_type(4)));
typedef unsigned short ushort_t;
typedef unsigned int u32;

__device__ __forceinline__ ushort_t f2bf(float f) {
    union { __hip_bfloat16 h; ushort_t u; } v;
    v.h = __float2bfloat16(f);
    return v.u;
}
__device__ __forceinline__ float bf2f(ushort_t h) {
    union { float f; u32 u; } v; v.u = ((u32)h) << 16;
    return v.f;
}

__device__ __forceinline__ void gl_lds16(const void* g, void* l) {
    __builtin_amdgcn_global_load_lds(
        (const __attribute__((address_space(1))) u32*)g,
        (__attribute__((address_space(3))) u32*)l, 16, 0, 0);
}

// cardinal cubic B-spline basis (8 funcs) + silu, closed form (== Cox-de Boor
// recursion of the reference on the uniform extended grid [-2.2,2.2], h=0.4).
__device__ __forceinline__ void basis_silu(float x, float w[8], float& sil) {
    sil = x / (1.0f + __expf(-x));
    float u  = (x + 2.2f) * 2.5f;
    float uf = floorf(u);
    int   j  = (int)uf;
    float t  = u - uf;
    float omt = 1.0f - t;
    float t2 = t * t, t3 = t2 * t;
    float w0 = omt * omt * omt * (1.0f / 6.0f);
    float w1 = (3.0f * t3 - 6.0f * t2 + 4.0f) * (1.0f / 6.0f);
    float w2 = (-3.0f * t3 + 3.0f * t2 + 3.0f * t + 1.0f) * (1.0f / 6.0f);
    float w3 = t3 * (1.0f / 6.0f);
    bool valid = (u >= 0.0f) && (u < 11.0f);
#pragma unroll
    for (int g = 0; g < 8; ++g) {
        int m = g - j + 3;
        float v = (m == 0) ? w0 : (m == 1) ? w1 : (m == 2) ? w2 : (m == 3) ? w3 : 0.0f;
        w[g] = valid ? v : 0.0f;
    }
}

__device__ __forceinline__ float selu_f(float x) {
    const float scale = 1.0507009873554805f;
    const float alpha = 1.6732632423543772f;
    return (x > 0.0f) ? scale * x : scale * alpha * (__expf(x) - 1.0f);
}

// ---------------------------------------------------------------------------
// kconv: 1152 blocks x 128 thr.  Blocks 0..383: A-conversion; 384..1151: W.
// ---------------------------------------------------------------------------
__global__ __launch_bounds__(128) void kconv(const float* __restrict__ x,
                                             const float* __restrict__ coef1,
                                             const float* __restrict__ sb1,
                                             const float* __restrict__ ssp1,
                                             char* __restrict__ Ag,
                                             char* __restrict__ Wg) {
    const int blk = blockIdx.x;
    if (blk < 384) {
        const int gid = blk * 128 + threadIdx.x;           // 0..49151
        const int b  = gid / 384;
        const int ig = gid - b * 384;
        const int i0 = ig * 8;

        float4 x0 = *reinterpret_cast<const float4*>(x + (size_t)b * IN1 + i0);
        float4 x1 = *reinterpret_cast<const float4*>(x + (size_t)b * IN1 + i0 + 4);
        float xa[8] = {x0.x, x0.y, x0.z, x0.w, x1.x, x1.y, x1.z, x1.w};

        float bs[8][8], sil[8];
#pragma unroll
        for (int p = 0; p < 8; ++p) basis_silu(xa[p], bs[p], sil[p]);

        char* rowp = Ag + (size_t)b * ROWB;
        const int qsw = ((ig & 7) ^ (b & 7)) << 4;
#pragma unroll
        for (int s = 0; s < 9; ++s) {
            ushort_t v[8];
#pragma unroll
            for (int p = 0; p < 8; ++p)
                v[p] = f2bf((s < 8) ? bs[p][s] : sil[p]);
            *reinterpret_cast<uint4*>(rowp + (s * 48 + (ig >> 3)) * 128 + qsw) =
                *reinterpret_cast<const uint4*>(v);
        }
    } else {
        const int gid = (blk - 384) * 128 + threadIdx.x;   // 0..98303
        const int o  = gid / 384;
        const int ig = gid - o * 384;
        const int i0 = ig * 8;

        float cf[8][8], sspv[8], sbv[8];
#pragma unroll
        for (int p = 0; p < 8; ++p) {
            const float* cp = coef1 + ((size_t)o * IN1 + i0 + p) * NB;
            float4 c0 = *reinterpret_cast<const float4*>(cp);
            float4 c1 = *reinterpret_cast<const float4*>(cp + 4);
            cf[p][0] = c0.x; cf[p][1] = c0.y; cf[p][2] = c0.z; cf[p][3] = c0.w;
            cf[p][4] = c1.x; cf[p][5] = c1.y; cf[p][6] = c1.z; cf[p][7] = c1.w;
        }
        {
            float4 s0 = *reinterpret_cast<const float4*>(ssp1 + (size_t)o * IN1 + i0);
            float4 s1 = *reinterpret_cast<const float4*>(ssp1 + (size_t)o * IN1 + i0 + 4);
            sspv[0]=s0.x; sspv[1]=s0.y; sspv[2]=s0.z; sspv[3]=s0.w;
            sspv[4]=s1.x; sspv[5]=s1.y; sspv[6]=s1.z; sspv[7]=s1.w;
            float4 b0 = *reinterpret_cast<const float4*>(sb1 + (size_t)o * IN1 + i0);
            float4 b1 = *reinterpret_cast<const float4*>(sb1 + (size_t)o * IN1 + i0 + 4);
            sbv[0]=b0.x; sbv[1]=b0.y; sbv[2]=b0.z; sbv[3]=b0.w;
            sbv[4]=b1.x; sbv[5]=b1.y; sbv[6]=b1.z; sbv[7]=b1.w;
        }

        char* rowp = Wg + (size_t)o * ROWB;
        const int qsw = ((ig & 7) ^ (o & 7)) << 4;
#pragma unroll
        for (int s = 0; s < 9; ++s) {
            ushort_t v[8];
#pragma unroll
            for (int p = 0; p < 8; ++p)
                v[p] = f2bf((s < 8) ? cf[p][s] * sspv[p] : sbv[p]);
            *reinterpret_cast<uint4*>(rowp + (s * 48 + (ig >> 3)) * 128 + qsw) =
                *reinterpret_cast<const uint4*>(v);
        }
    }
}

// ---------------------------------------------------------------------------
// kgemm: C(128 x 64-per-nt) += A(128,256k) * W(256k,64).  512 thr, grid (4,108).
//   Stage = 64 k (one 128B chunk per row).  2-buffer LDS, counted vmcnt.
//   Epilogue: bf16 partial [kc][b][o] (coalesced, contention-free).
// ---------------------------------------------------------------------------
__global__ __launch_bounds__(512) void kgemm(const char* __restrict__ Ag,
                                             const char* __restrict__ Wg,
                                             ushort_t* __restrict__ partial) {
    __shared__ __align__(16) char lds[2][24576];   // per buf: A 16K | W 8K

    const int tid = threadIdx.x;
    const int w   = tid >> 6, l = tid & 63;
    const int nt  = blockIdx.x, kc = blockIdx.y;
    const int o0  = nt * BN;

    const int ar0 = tid >> 3;                 // A round 0: rows 0..63
    const int ar1 = 64 + (tid >> 3);          // A round 1: rows 64..127
    const int aq  = tid & 7;
    const char* Asrc0 = Ag + (size_t)ar0 * ROWB + ((aq ^ (ar0 & 7)) << 4);
    const char* Asrc1 = Ag + (size_t)ar1 * ROWB + ((aq ^ (ar1 & 7)) << 4);
    const int wr = tid >> 3;                  // W rows 0..63
    const char* Wsrc = Wg + (size_t)(o0 + wr) * ROWB + ((aq ^ (wr & 7)) << 4);

#define ISSUE(ss, buf)                                                        \
    {                                                                         \
        const int cb = (kc * 4 + (ss)) * 128;                                 \
        char* base = &lds[buf][0];                                            \
        gl_lds16(Asrc0 + cb, base + w * 1024);                                \
        gl_lds16(Asrc1 + cb, base + 8192 + w * 1024);                         \
        gl_lds16(Wsrc  + cb, base + 16384 + w * 1024);                        \
    }

    f32x4 acc[2][2];
#pragma unroll
    for (int a = 0; a < 2; ++a)
#pragma unroll
        for (int bq = 0; bq < 2; ++bq) acc[a][bq] = (f32x4){0.f, 0.f, 0.f, 0.f};

    const int mq = w >> 1, nq = w & 1;
    const int r16 = l & 15, k16 = l >> 4;

    ISSUE(0, 0)
    ISSUE(1, 1)

#pragma unroll
    for (int s = 0; s < 4; ++s) {
        if (s < 3) { asm volatile("s_waitcnt vmcnt(3)" ::: "memory"); }
        else       { asm volatile("s_waitcnt vmcnt(0)" ::: "memory"); }
        __builtin_amdgcn_s_barrier();
        asm volatile("" ::: "memory");

        const char* Ab = &lds[s & 1][0];
        const char* Wb = &lds[s & 1][16384];
#pragma unroll
        for (int ks = 0; ks < 2; ++ks) {
            const int qf = ks * 4 + k16;
            bf16x8 bf[2], af[2];
#pragma unroll
            for (int bq = 0; bq < 2; ++bq) {
                const int rn = nq * 32 + bq * 16 + r16;
                bf[bq] = *reinterpret_cast<const bf16x8*>(Wb + rn * 128 + ((qf ^ (rn & 7)) << 4));
            }
#pragma unroll
            for (int a = 0; a < 2; ++a) {
                const int rm = mq * 32 + a * 16 + r16;
                af[a] = *reinterpret_cast<const bf16x8*>(Ab + rm * 128 + ((qf ^ (rm & 7)) << 4));
            }
#pragma unroll
            for (int a = 0; a < 2; ++a)
#pragma unroll
                for (int bq = 0; bq < 2; ++bq)
                    acc[a][bq] = __builtin_amdgcn_mfma_f32_16x16x32_bf16(af[a], bf[bq], acc[a][bq], 0, 0, 0);
        }

        __builtin_amdgcn_s_barrier();
        asm volatile("" ::: "memory");
        if (s == 0) ISSUE(2, 0)
        if (s == 1) ISSUE(3, 1)
    }
#undef ISSUE

    // epilogue: bf16 partial [kc][b][o]
    ushort_t* pp = partial + (size_t)kc * (B_DIM * OUT1);
#pragma unroll
    for (int a = 0; a < 2; ++a) {
#pragma unroll
        for (int bq = 0; bq < 2; ++bq) {
            const int col = o0 + nq * 32 + bq * 16 + r16;
#pragma unroll
            for (int r = 0; r < 4; ++r) {
                const int row = mq * 32 + a * 16 + k16 * 4 + r;
                pp[(size_t)row * OUT1 + col] = f2bf(acc[a][bq][r]);
            }
        }
    }
}

// ---------------------------------------------------------------------------
// klayer2r: one block per b, 256 thr (4 waves).
//   Wave w sums chunks kc = w+4c (c=0..26); lane l holds o = 4l..4l+3 via
//   ushort4 loads (512B contiguous per wave-load, 27 independent loads).
//   Then LDS combine -> h -> selu -> basis -> layer2 -> out.
// ---------------------------------------------------------------------------
__global__ __launch_bounds__(256) void klayer2r(const ushort_t* __restrict__ partial,
                                                const float* __restrict__ coef2,
                                                const float* __restrict__ sb2,
                                                const float* __restrict__ ssp2,
                                                float* __restrict__ out) {
    const int b = blockIdx.x;
    const int t = threadIdx.x;
    const int w = t >> 6, l = t & 63;

    f32x4 s = {0.f, 0.f, 0.f, 0.f};
    const ushort_t* pb = partial + (size_t)b * OUT1 + l * 4;
#pragma unroll
    for (int c = 0; c < 27; ++c) {
        ushort4 v = *reinterpret_cast<const ushort4*>(
            pb + (size_t)(w + 4 * c) * (B_DIM * OUT1));
        s[0] += bf2f(v.x); s[1] += bf2f(v.y); s[2] += bf2f(v.z); s[3] += bf2f(v.w);
    }

    __shared__ float sums[4][OUT1];
    *reinterpret_cast<float4*>(&sums[w][l * 4]) = (float4){s[0], s[1], s[2], s[3]};
    __syncthreads();

    const float hv = sums[0][t] + sums[1][t] + sums[2][t] + sums[3][t];
    const float sh = selu_f(hv);
    float w8[8], sil;
    basis_silu(sh, w8, sil);

    float accs[OUT2];
#pragma unroll
    for (int oo = 0; oo < OUT2; ++oo) {
        const float* cp = coef2 + ((size_t)oo * OUT1 + t) * NB;
        float4 c0 = *reinterpret_cast<const float4*>(cp);
        float4 c1 = *reinterpret_cast<const float4*>(cp + 4);
        float dot = w8[0] * c0.x + w8[1] * c0.y + w8[2] * c0.z + w8[3] * c0.w +
                    w8[4] * c1.x + w8[5] * c1.y + w8[6] * c1.z + w8[7] * c1.w;
        accs[oo] = sb2[oo * OUT1 + t] * sil + ssp2[oo * OUT1 + t] * dot;
    }

    __shared__ float red[4][OUT2];
#pragma unroll
    for (int oo = 0; oo < OUT2; ++oo) {
        float v = accs[oo];
#pragma unroll
        for (int off = 32; off >= 1; off >>= 1) v += __shfl_xor(v, off, 64);
        if (l == 0) red[w][oo] = v;
    }
    __syncthreads();
    if (t < OUT2)
        out[b * OUT2 + t] = red[0][t] + red[1][t] + red[2][t] + red[3][t];
}

// ---------------------------------------------------------------------------
extern "C" void kernel_launch(void* const* d_in, const int* in_sizes, int n_in,
                              void* d_out, int out_size, void* d_ws, size_t ws_size,
                              hipStream_t stream) {
    const float* x     = (const float*)d_in[0];
    const float* coef1 = (const float*)d_in[1];
    const float* sb1   = (const float*)d_in[2];
    const float* ssp1  = (const float*)d_in[3];
    const float* coef2 = (const float*)d_in[4];
    const float* sb2   = (const float*)d_in[5];
    const float* ssp2  = (const float*)d_in[6];
    float* out = (float*)d_out;

    char*     Ag      = (char*)d_ws;                             // 7,077,888 B
    char*     Wg      = Ag + (size_t)B_DIM * ROWB;               // 14,155,776 B
    ushort_t* partial = (ushort_t*)(Wg + (size_t)OUT1 * ROWB);   // 7,077,888 B

    kconv<<<1152, 128, 0, stream>>>(x, coef1, sb1, ssp1, Ag, Wg);
    kgemm<<<dim3(OUT1 / BN, SPLITK), 512, 0, stream>>>(Ag, Wg, partial);
    klayer2r<<<B_DIM, 256, 0, stream>>>(partial, coef2, sb2, ssp2, out);
}